// Round 7
// baseline (292.744 us; speedup 1.0000x reference)
//
#include <hip/hip_runtime.h>

#define NN  512
#define DD  128
#define NTASK_B 8448          // per-batch wave-tasks: 16 * (1+2+...+32)

typedef __attribute__((ext_vector_type(4))) float f32x4;
typedef __attribute__((ext_vector_type(8))) short s16x8;   // 8 bf16 (4 VGPRs)

#define MFMA(a, b, c) __builtin_amdgcn_mfma_f32_16x16x32_bf16((a), (b), (c), 0, 0, 0)

// LDS strides: keep 16B row alignment (ds_read_b128 requirement); padded
#define B1S 136   // 128 + 8 (ushort units)
#define B2S 72    // 64 + 8  (ushort units)
#define H1S 68    // 64 + 4  (u32 units)

// all-16-lane sum via DPP row rotations (VALU pipe, zero DS traffic)
#define ROR_ADD(x, CTRL) \
    ((x) + __int_as_float(__builtin_amdgcn_update_dpp(0, __float_as_int(x), (CTRL), 0xF, 0xF, true)))

// fp32 -> (bf16 hi [RNA], bf16 lo [trunc of exact remainder]); hh+lh+hl ~2^-17 rel
__device__ __forceinline__ void split8(const float* __restrict__ x, s16x8& h, s16x8& l) {
    uint4 hp, lp;
    unsigned* hw = (unsigned*)&hp;
    unsigned* lw = (unsigned*)&lp;
    #pragma unroll
    for (int i = 0; i < 4; ++i) {
        float x0 = x[2 * i], x1 = x[2 * i + 1];
        unsigned t0 = __float_as_uint(x0) + 0x8000u;
        unsigned t1 = __float_as_uint(x1) + 0x8000u;
        hw[i] = __builtin_amdgcn_perm(t1, t0, 0x07060302u);
        float l0 = x0 - __uint_as_float(t0 & 0xFFFF0000u);
        float l1 = x1 - __uint_as_float(t1 & 0xFFFF0000u);
        lw[i] = __builtin_amdgcn_perm(__float_as_uint(l1), __float_as_uint(l0), 0x07060302u);
    }
    h = __builtin_bit_cast(s16x8, hp);
    l = __builtin_bit_cast(s16x8, lp);
}

__device__ __forceinline__ void split1(float x, unsigned short& hs, unsigned short& ls) {
    unsigned tt = __float_as_uint(x) + 0x8000u;
    hs = (unsigned short)(tt >> 16);
    float lo = x - __uint_as_float(tt & 0xFFFF0000u);
    ls = (unsigned short)(__float_as_uint(lo) >> 16);
}

// pack one fp32 into u32 = (bf16_lo << 16) | bf16_hi  (same split math)
__device__ __forceinline__ unsigned packhl(float x) {
    unsigned tt = __float_as_uint(x) + 0x8000u;
    float lo = x - __uint_as_float(tt & 0xFFFF0000u);
    return __builtin_amdgcn_perm(__float_as_uint(lo), tt, 0x07060302u);
}

// 8 packed u32 -> hi-frag and lo-frag s16x8 (2 v_perm per pair of elems)
__device__ __forceinline__ void unpack8(const unsigned* __restrict__ u, s16x8& h, s16x8& l) {
    uint4 hp, lp;
    unsigned* hw = (unsigned*)&hp;
    unsigned* lw = (unsigned*)&lp;
    #pragma unroll
    for (int i = 0; i < 4; ++i) {
        hw[i] = __builtin_amdgcn_perm(u[2 * i + 1], u[2 * i], 0x05040100u);
        lw[i] = __builtin_amdgcn_perm(u[2 * i + 1], u[2 * i], 0x07060302u);
    }
    h = __builtin_bit_cast(s16x8, hp);
    l = __builtin_bit_cast(s16x8, lp);
}

// ---------------------------------------------------------------------------
// Round-1 structure (1-tile tasks, upfront xr loads) at 3 waves/SIMD:
// 512 persistent blocks x 6 waves (384 thr). 33792 tasks / 3072 waves = 11
// tasks/wave exactly. LDS 70144 B -> 2 blocks/CU = 12 waves/CU = 3/SIMD.
// DS diet vs r1: DPP reductions (no shfl_xor), packed-u32 h1.
// ---------------------------------------------------------------------------
__global__ __launch_bounds__(384, 3)
void adj_sym7(const float* __restrict__ v,
              const float* __restrict__ W1,
              const float* __restrict__ b1,
              const float* __restrict__ W2,
              const float* __restrict__ b2,
              const float* __restrict__ W3,
              const float* __restrict__ b3,
              float* __restrict__ out)
{
    __shared__ __attribute__((aligned(16))) unsigned short B1h_s[64 * B1S];
    __shared__ __attribute__((aligned(16))) unsigned short B1l_s[64 * B1S];
    __shared__ __attribute__((aligned(16))) unsigned short B2h_s[32 * B2S];
    __shared__ __attribute__((aligned(16))) unsigned short B2l_s[32 * B2S];
    __shared__ __attribute__((aligned(16))) unsigned h1p_s[96 * H1S];

    const int t    = threadIdx.x;
    const int w    = t >> 6;             // wave 0..5
    const int lane = t & 63;
    const int m16  = t & 15;
    const int q    = (t & 63) >> 4;
    const int q8   = q * 8;

    // ---- prologue: W1 split into LDS (2048 float4 over 384 threads) ----
    #pragma unroll
    for (int e = 0; e < 6; ++e) {
        int idx4 = e * 384 + t;
        if (idx4 < 2048) {
            int o = idx4 >> 5;
            int d = (idx4 & 31) * 4;
            float4 x = *(const float4*)(W1 + idx4 * 4);
            float xs[4] = {x.x, x.y, x.z, x.w};
            unsigned tb[4], lb[4];
            #pragma unroll
            for (int k2 = 0; k2 < 4; ++k2) {
                tb[k2] = __float_as_uint(xs[k2]) + 0x8000u;
                float lo = xs[k2] - __uint_as_float(tb[k2] & 0xFFFF0000u);
                lb[k2] = __float_as_uint(lo);
            }
            uint2 hw, lw;
            hw.x = __builtin_amdgcn_perm(tb[1], tb[0], 0x07060302u);
            hw.y = __builtin_amdgcn_perm(tb[3], tb[2], 0x07060302u);
            lw.x = __builtin_amdgcn_perm(lb[1], lb[0], 0x07060302u);
            lw.y = __builtin_amdgcn_perm(lb[3], lb[2], 0x07060302u);
            *(uint2*)(B1h_s + o * B1S + d) = hw;
            *(uint2*)(B1l_s + o * B1S + d) = lw;
        }
    }

    // ---- W2 split into LDS (2048 scalars over 384 threads) ----
    #pragma unroll
    for (int e = 0; e < 6; ++e) {
        int idx = e * 384 + t;
        if (idx < 2048) {
            unsigned short hs, ls;
            split1(W2[idx], hs, ls);
            int c2 = idx >> 6, k = idx & 63;
            B2h_s[c2 * B2S + k] = hs;
            B2l_s[c2 * B2S + k] = ls;
        }
    }

    float b1v[4];
    #pragma unroll
    for (int ot = 0; ot < 4; ++ot) b1v[ot] = b1[ot * 16 + m16];
    const float b2v0 = b2[m16];
    const float b2v1 = b2[16 + m16];
    const float w3v0 = W3[m16];
    const float w3v1 = W3[16 + m16];
    const float b3v  = b3[0];

    __syncthreads();   // B1/B2 ready; waves drift freely afterwards

    // ---- static per-wave chunk: exactly 11 tasks/wave ----
    const int g    = blockIdx.x * 6 + w;     // global wave 0..3071
    int       tk   = 11 * g;
    const int tend = tk + 11;

    // decode tk -> (bb, G, s, gj); task r = 8G(G+1) + s(G+1) + gj
    // i = 16G + s (row), j0 = 16*gj (col tile), gj <= G
    unsigned bb = (unsigned)tk / (unsigned)NTASK_B;
    int r = tk - (int)(bb * NTASK_B);
    int G = (int)((__fsqrt_rn((float)(2 * r + 1)) - 1.0f) * 0.25f);
    if (G < 0) G = 0;
    while (8 * (G + 1) * (G + 2) <= r) ++G;
    while (G > 0 && 8 * G * (G + 1) > r) --G;
    int rem = r - 8 * G * (G + 1);
    int s   = rem / (G + 1);
    int gj  = rem - s * (G + 1);
    bool newi = true;

    float yv[4][8];

    #pragma unroll 1
    for (; tk < tend; ++tk) {
        const size_t vb = (size_t)bb << 9;
        const int    i  = (G << 4) + s;
        const int    j0 = gj << 4;

        if (newi) {   // v_i slice (reused across the same-i run of j-tiles)
            const float* __restrict__ vip = v + (vb + (unsigned)i) * DD;
            #pragma unroll
            for (int kt = 0; kt < 4; ++kt) {
                *(float4*)&yv[kt][0] = *(const float4*)(vip + kt * 32 + q8);
                *(float4*)&yv[kt][4] = *(const float4*)(vip + kt * 32 + q8 + 4);
            }
        }

        // A-row slice, loaded UPFRONT (all 8 loads in flight together)
        const float* __restrict__ vr = v + (vb + (unsigned)(j0 + m16)) * DD;
        float xr[4][8];
        #pragma unroll
        for (int kt = 0; kt < 4; ++kt) {
            *(float4*)&xr[kt][0] = *(const float4*)(vr + kt * 32 + q8);
            *(float4*)&xr[kt][4] = *(const float4*)(vr + kt * 32 + q8 + 4);
        }

        // ======== layer 1: 16 pairs x 64 cols, K=128 ========
        f32x4 c[4];
        #pragma unroll
        for (int ot = 0; ot < 4; ++ot) c[ot] = (f32x4){0.f, 0.f, 0.f, 0.f};

        #pragma unroll
        for (int kt = 0; kt < 4; ++kt) {
            float d8[8];
            #pragma unroll
            for (int ii = 0; ii < 8; ++ii) d8[ii] = fabsf(yv[kt][ii] - xr[kt][ii]);
            s16x8 ah, al;
            split8(d8, ah, al);
            #pragma unroll
            for (int ot = 0; ot < 4; ++ot) {
                const int n = ot * 16 + m16;
                s16x8 bh = *(const s16x8*)(B1h_s + n * B1S + kt * 32 + q8);
                s16x8 bl = *(const s16x8*)(B1l_s + n * B1S + kt * 32 + q8);
                c[ot] = MFMA(ah, bh, c[ot]);
                c[ot] = MFMA(al, bh, c[ot]);
                c[ot] = MFMA(ah, bl, c[ot]);
            }
        }

        // bias + leaky -> wave-private packed h1 rows
        #pragma unroll
        for (int ot = 0; ot < 4; ++ot)
            #pragma unroll
            for (int rr = 0; rr < 4; ++rr) {
                float hv = c[ot][rr] + b1v[ot];
                hv = fmaxf(hv, 0.1f * hv);
                h1p_s[(w * 16 + q * 4 + rr) * H1S + ot * 16 + m16] = packhl(hv);
            }

        // ======== layer 2: 16 pairs x 32 cols, K=64 (B2 from LDS) ========
        f32x4 dacc0 = (f32x4){0.f, 0.f, 0.f, 0.f};
        f32x4 dacc1 = (f32x4){0.f, 0.f, 0.f, 0.f};
        #pragma unroll
        for (int kt2 = 0; kt2 < 2; ++kt2) {
            const unsigned* hp = h1p_s + (w * 16 + m16) * H1S + kt2 * 32 + q8;
            unsigned u[8];
            *(uint4*)&u[0] = *(const uint4*)hp;
            *(uint4*)&u[4] = *(const uint4*)(hp + 4);
            s16x8 ah, al;
            unpack8(u, ah, al);
            {
                s16x8 bh = *(const s16x8*)(B2h_s + m16 * B2S + kt2 * 32 + q8);
                s16x8 bl = *(const s16x8*)(B2l_s + m16 * B2S + kt2 * 32 + q8);
                dacc0 = MFMA(ah, bh, dacc0);
                dacc0 = MFMA(al, bh, dacc0);
                dacc0 = MFMA(ah, bl, dacc0);
            }
            {
                s16x8 bh = *(const s16x8*)(B2h_s + (16 + m16) * B2S + kt2 * 32 + q8);
                s16x8 bl = *(const s16x8*)(B2l_s + (16 + m16) * B2S + kt2 * 32 + q8);
                dacc1 = MFMA(ah, bh, dacc1);
                dacc1 = MFMA(al, bh, dacc1);
                dacc1 = MFMA(ah, bl, dacc1);
            }
        }

        // ======== layer 3 + DPP 16-lane reduce -> 16 logits ========
        float sval0, sval1, sval2, sval3;
        {
            float h0, h1v, sc;
            h0 = dacc0[0] + b2v0;  h0 = fmaxf(h0, 0.1f * h0);
            h1v = dacc1[0] + b2v1; h1v = fmaxf(h1v, 0.1f * h1v);
            sc = fmaf(w3v0, h0, w3v1 * h1v);
            sc = ROR_ADD(sc, 0x121); sc = ROR_ADD(sc, 0x122);
            sc = ROR_ADD(sc, 0x124); sc = ROR_ADD(sc, 0x128);
            sval0 = sc + b3v;
            h0 = dacc0[1] + b2v0;  h0 = fmaxf(h0, 0.1f * h0);
            h1v = dacc1[1] + b2v1; h1v = fmaxf(h1v, 0.1f * h1v);
            sc = fmaf(w3v0, h0, w3v1 * h1v);
            sc = ROR_ADD(sc, 0x121); sc = ROR_ADD(sc, 0x122);
            sc = ROR_ADD(sc, 0x124); sc = ROR_ADD(sc, 0x128);
            sval1 = sc + b3v;
            h0 = dacc0[2] + b2v0;  h0 = fmaxf(h0, 0.1f * h0);
            h1v = dacc1[2] + b2v1; h1v = fmaxf(h1v, 0.1f * h1v);
            sc = fmaf(w3v0, h0, w3v1 * h1v);
            sc = ROR_ADD(sc, 0x121); sc = ROR_ADD(sc, 0x122);
            sc = ROR_ADD(sc, 0x124); sc = ROR_ADD(sc, 0x128);
            sval2 = sc + b3v;
            h0 = dacc0[3] + b2v0;  h0 = fmaxf(h0, 0.1f * h0);
            h1v = dacc1[3] + b2v1; h1v = fmaxf(h1v, 0.1f * h1v);
            sc = fmaf(w3v0, h0, w3v1 * h1v);
            sc = ROR_ADD(sc, 0x121); sc = ROR_ADD(sc, 0x122);
            sc = ROR_ADD(sc, 0x124); sc = ROR_ADD(sc, 0x128);
            sval3 = sc + b3v;
        }
        // re-lane: lane L holds pair p = L&15 after one shfl
        const int p = lane & 15;
        float vv = sval0;
        vv = ((lane & 3) == 1) ? sval1 : vv;
        vv = ((lane & 3) == 2) ? sval2 : vv;
        vv = ((lane & 3) == 3) ? sval3 : vv;
        const float pv = __shfl(vv, ((p >> 2) << 4) | (p & 3), 64);

        if (lane < 32) {
            const size_t addr = (lane < 16)
                ? (vb + (unsigned)i) * NN + (unsigned)(j0 + p)        // direct row
                : (vb + (unsigned)(j0 + p)) * NN + (unsigned)i;       // mirror
            out[addr] = pv;
        }

        // ---- incremental task advance ----
        ++gj;
        newi = false;
        if (gj > G) {
            gj = 0; newi = true;
            if (++s == 16) {
                s = 0;
                if (++G == 32) { G = 0; ++bb; }
            }
        }
    }
}

// ---------------------------------------------------------------------------
// In-place row softmax over the 512 logits of each (b,i) row.
// ---------------------------------------------------------------------------
__global__ __launch_bounds__(256)
void row_softmax(float* __restrict__ out)
{
    __shared__ float red[8];
    const int t    = threadIdx.x;
    const int w    = t >> 6;
    const int lane = t & 63;

    float* orow = out + (size_t)blockIdx.x * NN;
    float a0 = orow[t];
    float a1 = orow[t + 256];

    float m = fmaxf(a0, a1);
    #pragma unroll
    for (int sh = 32; sh > 0; sh >>= 1)
        m = fmaxf(m, __shfl_xor(m, sh, 64));
    if (lane == 0) red[w] = m;
    __syncthreads();
    const float M = fmaxf(fmaxf(red[0], red[1]), fmaxf(red[2], red[3]));

    float e0 = __expf(a0 - M);
    float e1 = __expf(a1 - M);
    float s01 = e0 + e1;
    #pragma unroll
    for (int sh = 32; sh > 0; sh >>= 1)
        s01 += __shfl_xor(s01, sh, 64);
    if (lane == 0) red[4 + w] = s01;
    __syncthreads();
    const float S = (red[4] + red[5]) + (red[6] + red[7]);
    const float inv = 1.0f / S;

    orow[t]       = e0 * inv;
    orow[t + 256] = e1 * inv;
}

extern "C" void kernel_launch(void* const* d_in, const int* in_sizes, int n_in,
                              void* d_out, int out_size, void* d_ws, size_t ws_size,
                              hipStream_t stream) {
    const float* v  = (const float*)d_in[0];
    const float* W1 = (const float*)d_in[1];
    const float* b1 = (const float*)d_in[2];
    const float* W2 = (const float*)d_in[3];
    const float* b2 = (const float*)d_in[4];
    const float* W3 = (const float*)d_in[5];
    const float* b3 = (const float*)d_in[6];
    float* out = (float*)d_out;

    adj_sym7<<<dim3(512), dim3(384), 0, stream>>>(v, W1, b1, W2, b2, W3, b3, out);
    row_softmax<<<dim3(4 * NN), dim3(256), 0, stream>>>(out);
}

// Round 8
// 252.758 us; speedup vs baseline: 1.1582x; 1.1582x over previous
//
#include <hip/hip_runtime.h>

#define NN  512
#define DD  128
#define NTASK_B 8448          // per-batch wave-tasks: 16 * (1+2+...+32)

typedef __attribute__((ext_vector_type(4))) float f32x4;
typedef __attribute__((ext_vector_type(8))) short s16x8;   // 8 bf16 (4 VGPRs)

#define MFMA(a, b, c) __builtin_amdgcn_mfma_f32_16x16x32_bf16((a), (b), (c), 0, 0, 0)

// LDS strides: keep 16B row alignment (ds_read_b128) + break pow-2 banks
#define B1S 136   // 128 + 8 (ushort units)
#define B2S 72    // 64 + 8  (ushort units)

// all-16-lane sum via DPP row rotations (VALU pipe, zero DS traffic)
#define ROR_ADD(x, CTRL) \
    ((x) + __int_as_float(__builtin_amdgcn_update_dpp(0, __float_as_int(x), (CTRL), 0xF, 0xF, true)))

// fp32 -> (bf16 hi [RNA], bf16 lo [trunc of exact remainder]); hh+lh+hl ~2^-17 rel
__device__ __forceinline__ void split8(const float* __restrict__ x, s16x8& h, s16x8& l) {
    uint4 hp, lp;
    unsigned* hw = (unsigned*)&hp;
    unsigned* lw = (unsigned*)&lp;
    #pragma unroll
    for (int i = 0; i < 4; ++i) {
        float x0 = x[2 * i], x1 = x[2 * i + 1];
        unsigned t0 = __float_as_uint(x0) + 0x8000u;
        unsigned t1 = __float_as_uint(x1) + 0x8000u;
        hw[i] = __builtin_amdgcn_perm(t1, t0, 0x07060302u);
        float l0 = x0 - __uint_as_float(t0 & 0xFFFF0000u);
        float l1 = x1 - __uint_as_float(t1 & 0xFFFF0000u);
        lw[i] = __builtin_amdgcn_perm(__float_as_uint(l1), __float_as_uint(l0), 0x07060302u);
    }
    h = __builtin_bit_cast(s16x8, hp);
    l = __builtin_bit_cast(s16x8, lp);
}

__device__ __forceinline__ void split1(float x, unsigned short& hs, unsigned short& ls) {
    unsigned tt = __float_as_uint(x) + 0x8000u;
    hs = (unsigned short)(tt >> 16);
    float lo = x - __uint_as_float(tt & 0xFFFF0000u);
    ls = (unsigned short)(__float_as_uint(lo) >> 16);
}

// ---------------------------------------------------------------------------
// h1-in-registers via swapped layer-1 MFMA + pi-permuted W2 table.
// Layer 1: c[ot] = MFMA(W1frag, dfrag, c) -> lane (p=m16,q) holds channels
// ot*16+q*4+rr of pair p (lane-local). W2 cols stored at
// pi(c) = (ot&1)*32 + q*8 + (ot>>1)*4 + rr, so layer-2 A-frag is just
// {c[kt2][0..3], c[kt2+2][0..3]} -- NO h1 LDS, NO shuffles.
// LDS 44032 B -> 3 blocks/CU = 3 waves/SIMD. Grid 768 x 256, 11 tasks/wave.
// ---------------------------------------------------------------------------
__global__ __launch_bounds__(256, 3)
void adj_sym8(const float* __restrict__ v,
              const float* __restrict__ W1,
              const float* __restrict__ b1,
              const float* __restrict__ W2,
              const float* __restrict__ b2,
              const float* __restrict__ W3,
              const float* __restrict__ b3,
              float* __restrict__ out)
{
    __shared__ __attribute__((aligned(16))) unsigned short B1h_s[64 * B1S];
    __shared__ __attribute__((aligned(16))) unsigned short B1l_s[64 * B1S];
    __shared__ __attribute__((aligned(16))) unsigned short B2h_s[32 * B2S];
    __shared__ __attribute__((aligned(16))) unsigned short B2l_s[32 * B2S];

    const int t    = threadIdx.x;
    const int w    = t >> 6;             // wave 0..3
    const int lane = t & 63;
    const int m16  = t & 15;
    const int q    = (t & 63) >> 4;
    const int q8   = q * 8;

    // ---- prologue: W1 split into LDS, vectorized (8 x float4 per thread) ----
    #pragma unroll
    for (int e = 0; e < 8; ++e) {
        int idx4 = e * 256 + t;
        int o = idx4 >> 5;
        int d = (idx4 & 31) * 4;
        float4 x = *(const float4*)(W1 + idx4 * 4);
        float xs[4] = {x.x, x.y, x.z, x.w};
        unsigned tb[4], lb[4];
        #pragma unroll
        for (int k2 = 0; k2 < 4; ++k2) {
            tb[k2] = __float_as_uint(xs[k2]) + 0x8000u;
            float lo = xs[k2] - __uint_as_float(tb[k2] & 0xFFFF0000u);
            lb[k2] = __float_as_uint(lo);
        }
        uint2 hw, lw;
        hw.x = __builtin_amdgcn_perm(tb[1], tb[0], 0x07060302u);
        hw.y = __builtin_amdgcn_perm(tb[3], tb[2], 0x07060302u);
        lw.x = __builtin_amdgcn_perm(lb[1], lb[0], 0x07060302u);
        lw.y = __builtin_amdgcn_perm(lb[3], lb[2], 0x07060302u);
        *(uint2*)(B1h_s + o * B1S + d) = hw;
        *(uint2*)(B1l_s + o * B1S + d) = lw;
    }

    // ---- W2 split into LDS with pi-permuted columns ----
    #pragma unroll
    for (int e = 0; e < 8; ++e) {
        int idx = e * 256 + t;           // o2*64 + c
        int o2 = idx >> 6, c = idx & 63;
        int ot = c >> 4, cq = (c >> 2) & 3, rr = c & 3;
        int pos = (ot & 1) * 32 + cq * 8 + (ot >> 1) * 4 + rr;   // pi(c)
        unsigned short hs, ls;
        split1(W2[idx], hs, ls);
        B2h_s[o2 * B2S + pos] = hs;
        B2l_s[o2 * B2S + pos] = ls;
    }

    // per-lane bias for channels ot*16 + q*4 + rr (16 values)
    float b1v[4][4];
    #pragma unroll
    for (int ot = 0; ot < 4; ++ot)
        #pragma unroll
        for (int rr = 0; rr < 4; ++rr)
            b1v[ot][rr] = b1[ot * 16 + q * 4 + rr];
    const float b2v0 = b2[m16];
    const float b2v1 = b2[16 + m16];
    const float w3v0 = W3[m16];
    const float w3v1 = W3[16 + m16];
    const float b3v  = b3[0];

    __syncthreads();   // B1/B2 ready; waves drift freely afterwards

    // ---- static per-wave chunk: exactly 11 tasks/wave ----
    const int g    = blockIdx.x * 4 + w;     // global wave 0..3071
    int       tk   = 11 * g;
    const int tend = tk + 11;

    // decode tk -> (bb, G, s, gj); task r = 8G(G+1) + s(G+1) + gj
    // i = 16G + s (row), j0 = 16*gj (col tile), gj <= G
    unsigned bb = (unsigned)tk / (unsigned)NTASK_B;
    int r = tk - (int)(bb * NTASK_B);
    int G = (int)((__fsqrt_rn((float)(2 * r + 1)) - 1.0f) * 0.25f);
    if (G < 0) G = 0;
    while (8 * (G + 1) * (G + 2) <= r) ++G;
    while (G > 0 && 8 * G * (G + 1) > r) --G;
    int rem = r - 8 * G * (G + 1);
    int s   = rem / (G + 1);
    int gj  = rem - s * (G + 1);
    bool newi = true;

    float yv[4][8];

    #pragma unroll 1
    for (; tk < tend; ++tk) {
        const size_t vb = (size_t)bb << 9;
        const int    i  = (G << 4) + s;
        const int    j0 = gj << 4;

        if (newi) {   // v_i slice (reused across the same-i run of j-tiles)
            const float* __restrict__ vip = v + (vb + (unsigned)i) * DD;
            #pragma unroll
            for (int kt = 0; kt < 4; ++kt) {
                *(float4*)&yv[kt][0] = *(const float4*)(vip + kt * 32 + q8);
                *(float4*)&yv[kt][4] = *(const float4*)(vip + kt * 32 + q8 + 4);
            }
        }

        // A-row slice, loaded upfront (all 8 loads in flight together)
        const float* __restrict__ vr = v + (vb + (unsigned)(j0 + m16)) * DD;
        float xr[4][8];
        #pragma unroll
        for (int kt = 0; kt < 4; ++kt) {
            *(float4*)&xr[kt][0] = *(const float4*)(vr + kt * 32 + q8);
            *(float4*)&xr[kt][4] = *(const float4*)(vr + kt * 32 + q8 + 4);
        }

        // ======== layer 1 (SWAPPED): c[ot] rows=channels, cols=pairs ========
        f32x4 c[4];
        #pragma unroll
        for (int ot = 0; ot < 4; ++ot) c[ot] = (f32x4){0.f, 0.f, 0.f, 0.f};

        #pragma unroll
        for (int kt = 0; kt < 4; ++kt) {
            float d8[8];
            #pragma unroll
            for (int ii = 0; ii < 8; ++ii) d8[ii] = fabsf(yv[kt][ii] - xr[kt][ii]);
            s16x8 dh, dl;
            split8(d8, dh, dl);
            #pragma unroll
            for (int ot = 0; ot < 4; ++ot) {
                const int n = ot * 16 + m16;
                s16x8 bh = *(const s16x8*)(B1h_s + n * B1S + kt * 32 + q8);
                s16x8 bl = *(const s16x8*)(B1l_s + n * B1S + kt * 32 + q8);
                c[ot] = MFMA(bh, dh, c[ot]);   // Wh*dh
                c[ot] = MFMA(bl, dh, c[ot]);   // Wl*dh
                c[ot] = MFMA(bh, dl, c[ot]);   // Wh*dl
            }
        }

        // bias + leaky in registers (lane (p=m16,q): channel ot*16+q*4+rr)
        float hv[4][4];
        #pragma unroll
        for (int ot = 0; ot < 4; ++ot)
            #pragma unroll
            for (int rr = 0; rr < 4; ++rr) {
                float x = c[ot][rr] + b1v[ot][rr];
                hv[ot][rr] = fmaxf(x, 0.1f * x);
            }

        // ======== layer 2: A-frag direct from regs (pi-matched W2 table) =====
        f32x4 dacc0 = (f32x4){0.f, 0.f, 0.f, 0.f};
        f32x4 dacc1 = (f32x4){0.f, 0.f, 0.f, 0.f};
        #pragma unroll
        for (int kt2 = 0; kt2 < 2; ++kt2) {
            float a8[8];
            #pragma unroll
            for (int rr = 0; rr < 4; ++rr) {
                a8[rr]     = hv[kt2][rr];
                a8[4 + rr] = hv[kt2 + 2][rr];
            }
            s16x8 ah, al;
            split8(a8, ah, al);
            {
                s16x8 bh = *(const s16x8*)(B2h_s + m16 * B2S + kt2 * 32 + q8);
                s16x8 bl = *(const s16x8*)(B2l_s + m16 * B2S + kt2 * 32 + q8);
                dacc0 = MFMA(ah, bh, dacc0);
                dacc0 = MFMA(al, bh, dacc0);
                dacc0 = MFMA(ah, bl, dacc0);
            }
            {
                s16x8 bh = *(const s16x8*)(B2h_s + (16 + m16) * B2S + kt2 * 32 + q8);
                s16x8 bl = *(const s16x8*)(B2l_s + (16 + m16) * B2S + kt2 * 32 + q8);
                dacc1 = MFMA(ah, bh, dacc1);
                dacc1 = MFMA(al, bh, dacc1);
                dacc1 = MFMA(ah, bl, dacc1);
            }
        }

        // ======== layer 3 + DPP 16-lane reduce -> 16 logits ========
        float sval0, sval1, sval2, sval3;
        {
            float h0, h1v, sc;
            h0 = dacc0[0] + b2v0;  h0 = fmaxf(h0, 0.1f * h0);
            h1v = dacc1[0] + b2v1; h1v = fmaxf(h1v, 0.1f * h1v);
            sc = fmaf(w3v0, h0, w3v1 * h1v);
            sc = ROR_ADD(sc, 0x121); sc = ROR_ADD(sc, 0x122);
            sc = ROR_ADD(sc, 0x124); sc = ROR_ADD(sc, 0x128);
            sval0 = sc + b3v;
            h0 = dacc0[1] + b2v0;  h0 = fmaxf(h0, 0.1f * h0);
            h1v = dacc1[1] + b2v1; h1v = fmaxf(h1v, 0.1f * h1v);
            sc = fmaf(w3v0, h0, w3v1 * h1v);
            sc = ROR_ADD(sc, 0x121); sc = ROR_ADD(sc, 0x122);
            sc = ROR_ADD(sc, 0x124); sc = ROR_ADD(sc, 0x128);
            sval1 = sc + b3v;
            h0 = dacc0[2] + b2v0;  h0 = fmaxf(h0, 0.1f * h0);
            h1v = dacc1[2] + b2v1; h1v = fmaxf(h1v, 0.1f * h1v);
            sc = fmaf(w3v0, h0, w3v1 * h1v);
            sc = ROR_ADD(sc, 0x121); sc = ROR_ADD(sc, 0x122);
            sc = ROR_ADD(sc, 0x124); sc = ROR_ADD(sc, 0x128);
            sval2 = sc + b3v;
            h0 = dacc0[3] + b2v0;  h0 = fmaxf(h0, 0.1f * h0);
            h1v = dacc1[3] + b2v1; h1v = fmaxf(h1v, 0.1f * h1v);
            sc = fmaf(w3v0, h0, w3v1 * h1v);
            sc = ROR_ADD(sc, 0x121); sc = ROR_ADD(sc, 0x122);
            sc = ROR_ADD(sc, 0x124); sc = ROR_ADD(sc, 0x128);
            sval3 = sc + b3v;
        }
        // re-lane: lane L holds pair p = L&15 after one shfl
        const int p = lane & 15;
        float vv = sval0;
        vv = ((lane & 3) == 1) ? sval1 : vv;
        vv = ((lane & 3) == 2) ? sval2 : vv;
        vv = ((lane & 3) == 3) ? sval3 : vv;
        const float pv = __shfl(vv, ((p >> 2) << 4) | (p & 3), 64);

        if (lane < 32) {
            const size_t addr = (lane < 16)
                ? (vb + (unsigned)i) * NN + (unsigned)(j0 + p)        // direct row
                : (vb + (unsigned)(j0 + p)) * NN + (unsigned)i;       // mirror
            out[addr] = pv;
        }

        // ---- incremental task advance ----
        ++gj;
        newi = false;
        if (gj > G) {
            gj = 0; newi = true;
            if (++s == 16) {
                s = 0;
                if (++G == 32) { G = 0; ++bb; }
            }
        }
    }
}

// ---------------------------------------------------------------------------
// In-place row softmax over the 512 logits of each (b,i) row.
// ---------------------------------------------------------------------------
__global__ __launch_bounds__(256)
void row_softmax(float* __restrict__ out)
{
    __shared__ float red[8];
    const int t    = threadIdx.x;
    const int w    = t >> 6;
    const int lane = t & 63;

    float* orow = out + (size_t)blockIdx.x * NN;
    float a0 = orow[t];
    float a1 = orow[t + 256];

    float m = fmaxf(a0, a1);
    #pragma unroll
    for (int sh = 32; sh > 0; sh >>= 1)
        m = fmaxf(m, __shfl_xor(m, sh, 64));
    if (lane == 0) red[w] = m;
    __syncthreads();
    const float M = fmaxf(fmaxf(red[0], red[1]), fmaxf(red[2], red[3]));

    float e0 = __expf(a0 - M);
    float e1 = __expf(a1 - M);
    float s01 = e0 + e1;
    #pragma unroll
    for (int sh = 32; sh > 0; sh >>= 1)
        s01 += __shfl_xor(s01, sh, 64);
    if (lane == 0) red[4 + w] = s01;
    __syncthreads();
    const float S = (red[4] + red[5]) + (red[6] + red[7]);
    const float inv = 1.0f / S;

    orow[t]       = e0 * inv;
    orow[t + 256] = e1 * inv;
}

extern "C" void kernel_launch(void* const* d_in, const int* in_sizes, int n_in,
                              void* d_out, int out_size, void* d_ws, size_t ws_size,
                              hipStream_t stream) {
    const float* v  = (const float*)d_in[0];
    const float* W1 = (const float*)d_in[1];
    const float* b1 = (const float*)d_in[2];
    const float* W2 = (const float*)d_in[3];
    const float* b2 = (const float*)d_in[4];
    const float* W3 = (const float*)d_in[5];
    const float* b3 = (const float*)d_in[6];
    float* out = (float*)d_out;

    adj_sym8<<<dim3(768), dim3(256), 0, stream>>>(v, W1, b1, W2, b2, W3, b3, out);
    row_softmax<<<dim3(4 * NN), dim3(256), 0, stream>>>(out);
}

// Round 9
// 148.995 us; speedup vs baseline: 1.9648x; 1.6964x over previous
//
#include <hip/hip_runtime.h>

#define NN  512
#define DD  128
#define NTASK_B 8448          // per-batch wave-tasks: 16 * (1+2+...+32)

typedef __attribute__((ext_vector_type(4))) float f32x4;
typedef __attribute__((ext_vector_type(8))) short s16x8;   // 8 bf16 (4 VGPRs)

#define MFMA(a, b, c) __builtin_amdgcn_mfma_f32_16x16x32_bf16((a), (b), (c), 0, 0, 0)

// LDS strides: keep 16B row alignment (ds_read_b128) + break pow-2 banks
#define B1S 136   // 128 + 8 (ushort units)
#define B2S 72    // 64 + 8  (ushort units)

// all-16-lane sum via DPP row rotations (VALU pipe, zero DS traffic)
#define ROR_ADD(x, CTRL) \
    ((x) + __int_as_float(__builtin_amdgcn_update_dpp(0, __float_as_int(x), (CTRL), 0xF, 0xF, true)))

// fp32 -> (bf16 hi [RNA], bf16 lo [trunc of exact remainder]); hh+lh+hl ~2^-17 rel
__device__ __forceinline__ void split8(const float* __restrict__ x, s16x8& h, s16x8& l) {
    uint4 hp, lp;
    unsigned* hw = (unsigned*)&hp;
    unsigned* lw = (unsigned*)&lp;
    #pragma unroll
    for (int i = 0; i < 4; ++i) {
        float x0 = x[2 * i], x1 = x[2 * i + 1];
        unsigned t0 = __float_as_uint(x0) + 0x8000u;
        unsigned t1 = __float_as_uint(x1) + 0x8000u;
        hw[i] = __builtin_amdgcn_perm(t1, t0, 0x07060302u);
        float l0 = x0 - __uint_as_float(t0 & 0xFFFF0000u);
        float l1 = x1 - __uint_as_float(t1 & 0xFFFF0000u);
        lw[i] = __builtin_amdgcn_perm(__float_as_uint(l1), __float_as_uint(l0), 0x07060302u);
    }
    h = __builtin_bit_cast(s16x8, hp);
    l = __builtin_bit_cast(s16x8, lp);
}

__device__ __forceinline__ void split1(float x, unsigned short& hs, unsigned short& ls) {
    unsigned tt = __float_as_uint(x) + 0x8000u;
    hs = (unsigned short)(tt >> 16);
    float lo = x - __uint_as_float(tt & 0xFFFF0000u);
    ls = (unsigned short)(__float_as_uint(lo) >> 16);
}

// ---------------------------------------------------------------------------
// h1-in-registers via swapped layer-1 MFMA + pi-permuted W2 table
// (round-8 algorithm, hardware-verified correct) with the sane (256,2)
// register budget: allocator gets 256 unified regs -> no spill; HW may still
// co-schedule 3 blocks/CU since LDS=44032 and actual usage ~155 regs.
// Grid 768 x 256 (4 waves), exactly 11 tasks/wave.
// ---------------------------------------------------------------------------
__global__ __launch_bounds__(256, 2)
void adj_sym9(const float* __restrict__ v,
              const float* __restrict__ W1,
              const float* __restrict__ b1,
              const float* __restrict__ W2,
              const float* __restrict__ b2,
              const float* __restrict__ W3,
              const float* __restrict__ b3,
              float* __restrict__ out)
{
    __shared__ __attribute__((aligned(16))) unsigned short B1h_s[64 * B1S];
    __shared__ __attribute__((aligned(16))) unsigned short B1l_s[64 * B1S];
    __shared__ __attribute__((aligned(16))) unsigned short B2h_s[32 * B2S];
    __shared__ __attribute__((aligned(16))) unsigned short B2l_s[32 * B2S];

    const int t    = threadIdx.x;
    const int w    = t >> 6;             // wave 0..3
    const int lane = t & 63;
    const int m16  = t & 15;
    const int q    = (t & 63) >> 4;
    const int q8   = q * 8;

    // ---- prologue: W1 split into LDS, vectorized (8 x float4 per thread) ----
    #pragma unroll
    for (int e = 0; e < 8; ++e) {
        int idx4 = e * 256 + t;
        int o = idx4 >> 5;
        int d = (idx4 & 31) * 4;
        float4 x = *(const float4*)(W1 + idx4 * 4);
        float xs[4] = {x.x, x.y, x.z, x.w};
        unsigned tb[4], lb[4];
        #pragma unroll
        for (int k2 = 0; k2 < 4; ++k2) {
            tb[k2] = __float_as_uint(xs[k2]) + 0x8000u;
            float lo = xs[k2] - __uint_as_float(tb[k2] & 0xFFFF0000u);
            lb[k2] = __float_as_uint(lo);
        }
        uint2 hw, lw;
        hw.x = __builtin_amdgcn_perm(tb[1], tb[0], 0x07060302u);
        hw.y = __builtin_amdgcn_perm(tb[3], tb[2], 0x07060302u);
        lw.x = __builtin_amdgcn_perm(lb[1], lb[0], 0x07060302u);
        lw.y = __builtin_amdgcn_perm(lb[3], lb[2], 0x07060302u);
        *(uint2*)(B1h_s + o * B1S + d) = hw;
        *(uint2*)(B1l_s + o * B1S + d) = lw;
    }

    // ---- W2 split into LDS with pi-permuted columns ----
    #pragma unroll
    for (int e = 0; e < 8; ++e) {
        int idx = e * 256 + t;           // o2*64 + c
        int o2 = idx >> 6, c = idx & 63;
        int ot = c >> 4, cq = (c >> 2) & 3, rr = c & 3;
        int pos = (ot & 1) * 32 + cq * 8 + (ot >> 1) * 4 + rr;   // pi(c)
        unsigned short hs, ls;
        split1(W2[idx], hs, ls);
        B2h_s[o2 * B2S + pos] = hs;
        B2l_s[o2 * B2S + pos] = ls;
    }

    // per-lane bias for channels ot*16 + q*4 + rr (16 values)
    float b1v[4][4];
    #pragma unroll
    for (int ot = 0; ot < 4; ++ot)
        #pragma unroll
        for (int rr = 0; rr < 4; ++rr)
            b1v[ot][rr] = b1[ot * 16 + q * 4 + rr];
    const float b2v0 = b2[m16];
    const float b2v1 = b2[16 + m16];
    const float w3v0 = W3[m16];
    const float w3v1 = W3[16 + m16];
    const float b3v  = b3[0];

    __syncthreads();   // B1/B2 ready; waves drift freely afterwards

    // ---- static per-wave chunk: exactly 11 tasks/wave ----
    const int g    = blockIdx.x * 4 + w;     // global wave 0..3071
    int       tk   = 11 * g;
    const int tend = tk + 11;

    // decode tk -> (bb, G, s, gj); task r = 8G(G+1) + s(G+1) + gj
    // i = 16G + s (row), j0 = 16*gj (col tile), gj <= G
    unsigned bb = (unsigned)tk / (unsigned)NTASK_B;
    int r = tk - (int)(bb * NTASK_B);
    int G = (int)((__fsqrt_rn((float)(2 * r + 1)) - 1.0f) * 0.25f);
    if (G < 0) G = 0;
    while (8 * (G + 1) * (G + 2) <= r) ++G;
    while (G > 0 && 8 * G * (G + 1) > r) --G;
    int rem = r - 8 * G * (G + 1);
    int s   = rem / (G + 1);
    int gj  = rem - s * (G + 1);
    bool newi = true;

    float yv[4][8];

    #pragma unroll 1
    for (; tk < tend; ++tk) {
        const size_t vb = (size_t)bb << 9;
        const int    i  = (G << 4) + s;
        const int    j0 = gj << 4;

        if (newi) {   // v_i slice (reused across the same-i run of j-tiles)
            const float* __restrict__ vip = v + (vb + (unsigned)i) * DD;
            #pragma unroll
            for (int kt = 0; kt < 4; ++kt) {
                *(float4*)&yv[kt][0] = *(const float4*)(vip + kt * 32 + q8);
                *(float4*)&yv[kt][4] = *(const float4*)(vip + kt * 32 + q8 + 4);
            }
        }

        // A-row slice, loaded upfront (all 8 loads in flight together)
        const float* __restrict__ vr = v + (vb + (unsigned)(j0 + m16)) * DD;
        float xr[4][8];
        #pragma unroll
        for (int kt = 0; kt < 4; ++kt) {
            *(float4*)&xr[kt][0] = *(const float4*)(vr + kt * 32 + q8);
            *(float4*)&xr[kt][4] = *(const float4*)(vr + kt * 32 + q8 + 4);
        }

        // ======== layer 1 (SWAPPED): c[ot] rows=channels, cols=pairs ========
        f32x4 c[4];
        #pragma unroll
        for (int ot = 0; ot < 4; ++ot) c[ot] = (f32x4){0.f, 0.f, 0.f, 0.f};

        #pragma unroll
        for (int kt = 0; kt < 4; ++kt) {
            float d8[8];
            #pragma unroll
            for (int ii = 0; ii < 8; ++ii) d8[ii] = fabsf(yv[kt][ii] - xr[kt][ii]);
            s16x8 dh, dl;
            split8(d8, dh, dl);
            #pragma unroll
            for (int ot = 0; ot < 4; ++ot) {
                const int n = ot * 16 + m16;
                s16x8 bh = *(const s16x8*)(B1h_s + n * B1S + kt * 32 + q8);
                s16x8 bl = *(const s16x8*)(B1l_s + n * B1S + kt * 32 + q8);
                c[ot] = MFMA(bh, dh, c[ot]);   // Wh*dh
                c[ot] = MFMA(bl, dh, c[ot]);   // Wl*dh
                c[ot] = MFMA(bh, dl, c[ot]);   // Wh*dl
            }
        }

        // bias + leaky in registers (lane (p=m16,q): channel ot*16+q*4+rr)
        float hv[4][4];
        #pragma unroll
        for (int ot = 0; ot < 4; ++ot)
            #pragma unroll
            for (int rr = 0; rr < 4; ++rr) {
                float x = c[ot][rr] + b1v[ot][rr];
                hv[ot][rr] = fmaxf(x, 0.1f * x);
            }

        // ======== layer 2: A-frag direct from regs (pi-matched W2 table) =====
        f32x4 dacc0 = (f32x4){0.f, 0.f, 0.f, 0.f};
        f32x4 dacc1 = (f32x4){0.f, 0.f, 0.f, 0.f};
        #pragma unroll
        for (int kt2 = 0; kt2 < 2; ++kt2) {
            float a8[8];
            #pragma unroll
            for (int rr = 0; rr < 4; ++rr) {
                a8[rr]     = hv[kt2][rr];
                a8[4 + rr] = hv[kt2 + 2][rr];
            }
            s16x8 ah, al;
            split8(a8, ah, al);
            {
                s16x8 bh = *(const s16x8*)(B2h_s + m16 * B2S + kt2 * 32 + q8);
                s16x8 bl = *(const s16x8*)(B2l_s + m16 * B2S + kt2 * 32 + q8);
                dacc0 = MFMA(ah, bh, dacc0);
                dacc0 = MFMA(al, bh, dacc0);
                dacc0 = MFMA(ah, bl, dacc0);
            }
            {
                s16x8 bh = *(const s16x8*)(B2h_s + (16 + m16) * B2S + kt2 * 32 + q8);
                s16x8 bl = *(const s16x8*)(B2l_s + (16 + m16) * B2S + kt2 * 32 + q8);
                dacc1 = MFMA(ah, bh, dacc1);
                dacc1 = MFMA(al, bh, dacc1);
                dacc1 = MFMA(ah, bl, dacc1);
            }
        }

        // ======== layer 3 + DPP 16-lane reduce -> 16 logits ========
        float sval0, sval1, sval2, sval3;
        {
            float h0, h1v, sc;
            h0 = dacc0[0] + b2v0;  h0 = fmaxf(h0, 0.1f * h0);
            h1v = dacc1[0] + b2v1; h1v = fmaxf(h1v, 0.1f * h1v);
            sc = fmaf(w3v0, h0, w3v1 * h1v);
            sc = ROR_ADD(sc, 0x121); sc = ROR_ADD(sc, 0x122);
            sc = ROR_ADD(sc, 0x124); sc = ROR_ADD(sc, 0x128);
            sval0 = sc + b3v;
            h0 = dacc0[1] + b2v0;  h0 = fmaxf(h0, 0.1f * h0);
            h1v = dacc1[1] + b2v1; h1v = fmaxf(h1v, 0.1f * h1v);
            sc = fmaf(w3v0, h0, w3v1 * h1v);
            sc = ROR_ADD(sc, 0x121); sc = ROR_ADD(sc, 0x122);
            sc = ROR_ADD(sc, 0x124); sc = ROR_ADD(sc, 0x128);
            sval1 = sc + b3v;
            h0 = dacc0[2] + b2v0;  h0 = fmaxf(h0, 0.1f * h0);
            h1v = dacc1[2] + b2v1; h1v = fmaxf(h1v, 0.1f * h1v);
            sc = fmaf(w3v0, h0, w3v1 * h1v);
            sc = ROR_ADD(sc, 0x121); sc = ROR_ADD(sc, 0x122);
            sc = ROR_ADD(sc, 0x124); sc = ROR_ADD(sc, 0x128);
            sval2 = sc + b3v;
            h0 = dacc0[3] + b2v0;  h0 = fmaxf(h0, 0.1f * h0);
            h1v = dacc1[3] + b2v1; h1v = fmaxf(h1v, 0.1f * h1v);
            sc = fmaf(w3v0, h0, w3v1 * h1v);
            sc = ROR_ADD(sc, 0x121); sc = ROR_ADD(sc, 0x122);
            sc = ROR_ADD(sc, 0x124); sc = ROR_ADD(sc, 0x128);
            sval3 = sc + b3v;
        }
        // re-lane: lane L holds pair p = L&15 after one shfl
        const int p = lane & 15;
        float vv = sval0;
        vv = ((lane & 3) == 1) ? sval1 : vv;
        vv = ((lane & 3) == 2) ? sval2 : vv;
        vv = ((lane & 3) == 3) ? sval3 : vv;
        const float pv = __shfl(vv, ((p >> 2) << 4) | (p & 3), 64);

        if (lane < 32) {
            const size_t addr = (lane < 16)
                ? (vb + (unsigned)i) * NN + (unsigned)(j0 + p)        // direct row
                : (vb + (unsigned)(j0 + p)) * NN + (unsigned)i;       // mirror
            out[addr] = pv;
        }

        // ---- incremental task advance ----
        ++gj;
        newi = false;
        if (gj > G) {
            gj = 0; newi = true;
            if (++s == 16) {
                s = 0;
                if (++G == 32) { G = 0; ++bb; }
            }
        }
    }
}

// ---------------------------------------------------------------------------
// In-place row softmax over the 512 logits of each (b,i) row.
// ---------------------------------------------------------------------------
__global__ __launch_bounds__(256)
void row_softmax(float* __restrict__ out)
{
    __shared__ float red[8];
    const int t    = threadIdx.x;
    const int w    = t >> 6;
    const int lane = t & 63;

    float* orow = out + (size_t)blockIdx.x * NN;
    float a0 = orow[t];
    float a1 = orow[t + 256];

    float m = fmaxf(a0, a1);
    #pragma unroll
    for (int sh = 32; sh > 0; sh >>= 1)
        m = fmaxf(m, __shfl_xor(m, sh, 64));
    if (lane == 0) red[w] = m;
    __syncthreads();
    const float M = fmaxf(fmaxf(red[0], red[1]), fmaxf(red[2], red[3]));

    float e0 = __expf(a0 - M);
    float e1 = __expf(a1 - M);
    float s01 = e0 + e1;
    #pragma unroll
    for (int sh = 32; sh > 0; sh >>= 1)
        s01 += __shfl_xor(s01, sh, 64);
    if (lane == 0) red[4 + w] = s01;
    __syncthreads();
    const float S = (red[4] + red[5]) + (red[6] + red[7]);
    const float inv = 1.0f / S;

    orow[t]       = e0 * inv;
    orow[t + 256] = e1 * inv;
}

extern "C" void kernel_launch(void* const* d_in, const int* in_sizes, int n_in,
                              void* d_out, int out_size, void* d_ws, size_t ws_size,
                              hipStream_t stream) {
    const float* v  = (const float*)d_in[0];
    const float* W1 = (const float*)d_in[1];
    const float* b1 = (const float*)d_in[2];
    const float* W2 = (const float*)d_in[3];
    const float* b2 = (const float*)d_in[4];
    const float* W3 = (const float*)d_in[5];
    const float* b3 = (const float*)d_in[6];
    float* out = (float*)d_out;

    adj_sym9<<<dim3(768), dim3(256), 0, stream>>>(v, W1, b1, W2, b2, W3, b3, out);
    row_softmax<<<dim3(4 * NN), dim3(256), 0, stream>>>(out);
}

// Round 10
// 130.719 us; speedup vs baseline: 2.2395x; 1.1398x over previous
//
#include <hip/hip_runtime.h>

#define NN  512
#define DD  128
#define NTASK_B 8448          // per-batch wave-tasks: 16 * (1+2+...+32)

typedef __attribute__((ext_vector_type(4))) float f32x4;
typedef __attribute__((ext_vector_type(8))) short s16x8;   // 8 bf16 (4 VGPRs)

#define MFMA(a, b, c) __builtin_amdgcn_mfma_f32_16x16x32_bf16((a), (b), (c), 0, 0, 0)

// LDS strides: keep 16B row alignment (ds_read_b128) + break pow-2 banks
#define B1S 136   // 128 + 8 (ushort units)
#define B2S 72    // 64 + 8  (ushort units)

// all-16-lane sum via DPP row rotations (VALU pipe, zero DS traffic)
#define ROR_ADD(x, CTRL) \
    ((x) + __int_as_float(__builtin_amdgcn_update_dpp(0, __float_as_int(x), (CTRL), 0xF, 0xF, true)))

// fp32 -> (bf16 hi [RNA], bf16 lo [trunc of exact remainder]); hh+lh+hl ~2^-17 rel
__device__ __forceinline__ void split8(const float* __restrict__ x, s16x8& h, s16x8& l) {
    uint4 hp, lp;
    unsigned* hw = (unsigned*)&hp;
    unsigned* lw = (unsigned*)&lp;
    #pragma unroll
    for (int i = 0; i < 4; ++i) {
        float x0 = x[2 * i], x1 = x[2 * i + 1];
        unsigned t0 = __float_as_uint(x0) + 0x8000u;
        unsigned t1 = __float_as_uint(x1) + 0x8000u;
        hw[i] = __builtin_amdgcn_perm(t1, t0, 0x07060302u);
        float l0 = x0 - __uint_as_float(t0 & 0xFFFF0000u);
        float l1 = x1 - __uint_as_float(t1 & 0xFFFF0000u);
        lw[i] = __builtin_amdgcn_perm(__float_as_uint(l1), __float_as_uint(l0), 0x07060302u);
    }
    h = __builtin_bit_cast(s16x8, hp);
    l = __builtin_bit_cast(s16x8, lp);
}

__device__ __forceinline__ void split1(float x, unsigned short& hs, unsigned short& ls) {
    unsigned tt = __float_as_uint(x) + 0x8000u;
    hs = (unsigned short)(tt >> 16);
    float lo = x - __uint_as_float(tt & 0xFFFF0000u);
    ls = (unsigned short)(__float_as_uint(lo) >> 16);
}

// ---------------------------------------------------------------------------
// Structure B (h1-in-registers via swapped layer-1 MFMA + pi-permuted W2,
// HW-verified r8/r9) on the proven single-shift geometry: grid 512 x 256,
// 2 blocks/CU exactly (reg cap: ~128 arch + ~64 acc = 192/wave -> 2/SIMD),
// 16.5 tasks/wave (r1 chunking). One cohort, no straggler shift.
// ---------------------------------------------------------------------------
__global__ __launch_bounds__(256, 2)
void adj_sym10(const float* __restrict__ v,
               const float* __restrict__ W1,
               const float* __restrict__ b1,
               const float* __restrict__ W2,
               const float* __restrict__ b2,
               const float* __restrict__ W3,
               const float* __restrict__ b3,
               float* __restrict__ out)
{
    __shared__ __attribute__((aligned(16))) unsigned short B1h_s[64 * B1S];
    __shared__ __attribute__((aligned(16))) unsigned short B1l_s[64 * B1S];
    __shared__ __attribute__((aligned(16))) unsigned short B2h_s[32 * B2S];
    __shared__ __attribute__((aligned(16))) unsigned short B2l_s[32 * B2S];

    const int t    = threadIdx.x;
    const int w    = t >> 6;             // wave 0..3
    const int lane = t & 63;
    const int m16  = t & 15;
    const int q    = (t & 63) >> 4;
    const int q8   = q * 8;

    // ---- prologue: W1 split into LDS, vectorized (8 x float4 per thread) ----
    #pragma unroll
    for (int e = 0; e < 8; ++e) {
        int idx4 = e * 256 + t;
        int o = idx4 >> 5;
        int d = (idx4 & 31) * 4;
        float4 x = *(const float4*)(W1 + idx4 * 4);
        float xs[4] = {x.x, x.y, x.z, x.w};
        unsigned tb[4], lb[4];
        #pragma unroll
        for (int k2 = 0; k2 < 4; ++k2) {
            tb[k2] = __float_as_uint(xs[k2]) + 0x8000u;
            float lo = xs[k2] - __uint_as_float(tb[k2] & 0xFFFF0000u);
            lb[k2] = __float_as_uint(lo);
        }
        uint2 hw, lw;
        hw.x = __builtin_amdgcn_perm(tb[1], tb[0], 0x07060302u);
        hw.y = __builtin_amdgcn_perm(tb[3], tb[2], 0x07060302u);
        lw.x = __builtin_amdgcn_perm(lb[1], lb[0], 0x07060302u);
        lw.y = __builtin_amdgcn_perm(lb[3], lb[2], 0x07060302u);
        *(uint2*)(B1h_s + o * B1S + d) = hw;
        *(uint2*)(B1l_s + o * B1S + d) = lw;
    }

    // ---- W2 split into LDS with pi-permuted columns ----
    #pragma unroll
    for (int e = 0; e < 8; ++e) {
        int idx = e * 256 + t;           // o2*64 + c
        int o2 = idx >> 6, c = idx & 63;
        int ot = c >> 4, cq = (c >> 2) & 3, rr = c & 3;
        int pos = (ot & 1) * 32 + cq * 8 + (ot >> 1) * 4 + rr;   // pi(c)
        unsigned short hs, ls;
        split1(W2[idx], hs, ls);
        B2h_s[o2 * B2S + pos] = hs;
        B2l_s[o2 * B2S + pos] = ls;
    }

    // per-lane bias for channels ot*16 + q*4 + rr (16 values)
    float b1v[4][4];
    #pragma unroll
    for (int ot = 0; ot < 4; ++ot)
        #pragma unroll
        for (int rr = 0; rr < 4; ++rr)
            b1v[ot][rr] = b1[ot * 16 + q * 4 + rr];
    const float b2v0 = b2[m16];
    const float b2v1 = b2[16 + m16];
    const float w3v0 = W3[m16];
    const float w3v1 = W3[16 + m16];
    const float b3v  = b3[0];

    __syncthreads();   // B1/B2 ready; waves drift freely afterwards

    // ---- static per-wave chunk: 16.5 tasks/wave (r1 chunking) ----
    const int g    = blockIdx.x * 4 + w;     // global wave 0..2047
    int       tk   = (33 * g) >> 1;
    const int tend = (33 * (g + 1)) >> 1;

    // decode tk -> (bb, G, s, gj); task r = 8G(G+1) + s(G+1) + gj
    // i = 16G + s (row), j0 = 16*gj (col tile), gj <= G
    unsigned bb = (unsigned)tk / (unsigned)NTASK_B;
    int r = tk - (int)(bb * NTASK_B);
    int G = (int)((__fsqrt_rn((float)(2 * r + 1)) - 1.0f) * 0.25f);
    if (G < 0) G = 0;
    while (8 * (G + 1) * (G + 2) <= r) ++G;
    while (G > 0 && 8 * G * (G + 1) > r) --G;
    int rem = r - 8 * G * (G + 1);
    int s   = rem / (G + 1);
    int gj  = rem - s * (G + 1);
    bool newi = true;

    float yv[4][8];

    #pragma unroll 1
    for (; tk < tend; ++tk) {
        const size_t vb = (size_t)bb << 9;
        const int    i  = (G << 4) + s;
        const int    j0 = gj << 4;

        if (newi) {   // v_i slice (reused across the same-i run of j-tiles)
            const float* __restrict__ vip = v + (vb + (unsigned)i) * DD;
            #pragma unroll
            for (int kt = 0; kt < 4; ++kt) {
                *(float4*)&yv[kt][0] = *(const float4*)(vip + kt * 32 + q8);
                *(float4*)&yv[kt][4] = *(const float4*)(vip + kt * 32 + q8 + 4);
            }
        }

        // A-row slice, loaded upfront (all 8 loads in flight together)
        const float* __restrict__ vr = v + (vb + (unsigned)(j0 + m16)) * DD;
        float xr[4][8];
        #pragma unroll
        for (int kt = 0; kt < 4; ++kt) {
            *(float4*)&xr[kt][0] = *(const float4*)(vr + kt * 32 + q8);
            *(float4*)&xr[kt][4] = *(const float4*)(vr + kt * 32 + q8 + 4);
        }

        // ======== layer 1 (SWAPPED): c[ot] rows=channels, cols=pairs ========
        f32x4 c[4];
        #pragma unroll
        for (int ot = 0; ot < 4; ++ot) c[ot] = (f32x4){0.f, 0.f, 0.f, 0.f};

        #pragma unroll
        for (int kt = 0; kt < 4; ++kt) {
            float d8[8];
            #pragma unroll
            for (int ii = 0; ii < 8; ++ii) d8[ii] = fabsf(yv[kt][ii] - xr[kt][ii]);
            s16x8 dh, dl;
            split8(d8, dh, dl);
            #pragma unroll
            for (int ot = 0; ot < 4; ++ot) {
                const int n = ot * 16 + m16;
                s16x8 bh = *(const s16x8*)(B1h_s + n * B1S + kt * 32 + q8);
                s16x8 bl = *(const s16x8*)(B1l_s + n * B1S + kt * 32 + q8);
                c[ot] = MFMA(bh, dh, c[ot]);   // Wh*dh
                c[ot] = MFMA(bl, dh, c[ot]);   // Wl*dh
                c[ot] = MFMA(bh, dl, c[ot]);   // Wh*dl
            }
        }

        // bias + leaky in registers (lane (p=m16,q): channel ot*16+q*4+rr)
        float hv[4][4];
        #pragma unroll
        for (int ot = 0; ot < 4; ++ot)
            #pragma unroll
            for (int rr = 0; rr < 4; ++rr) {
                float x = c[ot][rr] + b1v[ot][rr];
                hv[ot][rr] = fmaxf(x, 0.1f * x);
            }

        // ======== layer 2: A-frag direct from regs (pi-matched W2 table) =====
        f32x4 dacc0 = (f32x4){0.f, 0.f, 0.f, 0.f};
        f32x4 dacc1 = (f32x4){0.f, 0.f, 0.f, 0.f};
        #pragma unroll
        for (int kt2 = 0; kt2 < 2; ++kt2) {
            float a8[8];
            #pragma unroll
            for (int rr = 0; rr < 4; ++rr) {
                a8[rr]     = hv[kt2][rr];
                a8[4 + rr] = hv[kt2 + 2][rr];
            }
            s16x8 ah, al;
            split8(a8, ah, al);
            {
                s16x8 bh = *(const s16x8*)(B2h_s + m16 * B2S + kt2 * 32 + q8);
                s16x8 bl = *(const s16x8*)(B2l_s + m16 * B2S + kt2 * 32 + q8);
                dacc0 = MFMA(ah, bh, dacc0);
                dacc0 = MFMA(al, bh, dacc0);
                dacc0 = MFMA(ah, bl, dacc0);
            }
            {
                s16x8 bh = *(const s16x8*)(B2h_s + (16 + m16) * B2S + kt2 * 32 + q8);
                s16x8 bl = *(const s16x8*)(B2l_s + (16 + m16) * B2S + kt2 * 32 + q8);
                dacc1 = MFMA(ah, bh, dacc1);
                dacc1 = MFMA(al, bh, dacc1);
                dacc1 = MFMA(ah, bl, dacc1);
            }
        }

        // ======== layer 3 + DPP 16-lane reduce -> 16 logits ========
        float sval0, sval1, sval2, sval3;
        {
            float h0, h1v, sc;
            h0 = dacc0[0] + b2v0;  h0 = fmaxf(h0, 0.1f * h0);
            h1v = dacc1[0] + b2v1; h1v = fmaxf(h1v, 0.1f * h1v);
            sc = fmaf(w3v0, h0, w3v1 * h1v);
            sc = ROR_ADD(sc, 0x121); sc = ROR_ADD(sc, 0x122);
            sc = ROR_ADD(sc, 0x124); sc = ROR_ADD(sc, 0x128);
            sval0 = sc + b3v;
            h0 = dacc0[1] + b2v0;  h0 = fmaxf(h0, 0.1f * h0);
            h1v = dacc1[1] + b2v1; h1v = fmaxf(h1v, 0.1f * h1v);
            sc = fmaf(w3v0, h0, w3v1 * h1v);
            sc = ROR_ADD(sc, 0x121); sc = ROR_ADD(sc, 0x122);
            sc = ROR_ADD(sc, 0x124); sc = ROR_ADD(sc, 0x128);
            sval1 = sc + b3v;
            h0 = dacc0[2] + b2v0;  h0 = fmaxf(h0, 0.1f * h0);
            h1v = dacc1[2] + b2v1; h1v = fmaxf(h1v, 0.1f * h1v);
            sc = fmaf(w3v0, h0, w3v1 * h1v);
            sc = ROR_ADD(sc, 0x121); sc = ROR_ADD(sc, 0x122);
            sc = ROR_ADD(sc, 0x124); sc = ROR_ADD(sc, 0x128);
            sval2 = sc + b3v;
            h0 = dacc0[3] + b2v0;  h0 = fmaxf(h0, 0.1f * h0);
            h1v = dacc1[3] + b2v1; h1v = fmaxf(h1v, 0.1f * h1v);
            sc = fmaf(w3v0, h0, w3v1 * h1v);
            sc = ROR_ADD(sc, 0x121); sc = ROR_ADD(sc, 0x122);
            sc = ROR_ADD(sc, 0x124); sc = ROR_ADD(sc, 0x128);
            sval3 = sc + b3v;
        }
        // re-lane: lane L holds pair p = L&15 after one shfl
        const int p = lane & 15;
        float vv = sval0;
        vv = ((lane & 3) == 1) ? sval1 : vv;
        vv = ((lane & 3) == 2) ? sval2 : vv;
        vv = ((lane & 3) == 3) ? sval3 : vv;
        const float pv = __shfl(vv, ((p >> 2) << 4) | (p & 3), 64);

        if (lane < 32) {
            const size_t addr = (lane < 16)
                ? (vb + (unsigned)i) * NN + (unsigned)(j0 + p)        // direct row
                : (vb + (unsigned)(j0 + p)) * NN + (unsigned)i;       // mirror
            out[addr] = pv;
        }

        // ---- incremental task advance ----
        ++gj;
        newi = false;
        if (gj > G) {
            gj = 0; newi = true;
            if (++s == 16) {
                s = 0;
                if (++G == 32) { G = 0; ++bb; }
            }
        }
    }
}

// ---------------------------------------------------------------------------
// In-place row softmax over the 512 logits of each (b,i) row.
// ---------------------------------------------------------------------------
__global__ __launch_bounds__(256)
void row_softmax(float* __restrict__ out)
{
    __shared__ float red[8];
    const int t    = threadIdx.x;
    const int w    = t >> 6;
    const int lane = t & 63;

    float* orow = out + (size_t)blockIdx.x * NN;
    float a0 = orow[t];
    float a1 = orow[t + 256];

    float m = fmaxf(a0, a1);
    #pragma unroll
    for (int sh = 32; sh > 0; sh >>= 1)
        m = fmaxf(m, __shfl_xor(m, sh, 64));
    if (lane == 0) red[w] = m;
    __syncthreads();
    const float M = fmaxf(fmaxf(red[0], red[1]), fmaxf(red[2], red[3]));

    float e0 = __expf(a0 - M);
    float e1 = __expf(a1 - M);
    float s01 = e0 + e1;
    #pragma unroll
    for (int sh = 32; sh > 0; sh >>= 1)
        s01 += __shfl_xor(s01, sh, 64);
    if (lane == 0) red[4 + w] = s01;
    __syncthreads();
    const float S = (red[4] + red[5]) + (red[6] + red[7]);
    const float inv = 1.0f / S;

    orow[t]       = e0 * inv;
    orow[t + 256] = e1 * inv;
}

extern "C" void kernel_launch(void* const* d_in, const int* in_sizes, int n_in,
                              void* d_out, int out_size, void* d_ws, size_t ws_size,
                              hipStream_t stream) {
    const float* v  = (const float*)d_in[0];
    const float* W1 = (const float*)d_in[1];
    const float* b1 = (const float*)d_in[2];
    const float* W2 = (const float*)d_in[3];
    const float* b2 = (const float*)d_in[4];
    const float* W3 = (const float*)d_in[5];
    const float* b3 = (const float*)d_in[6];
    float* out = (float*)d_out;

    adj_sym10<<<dim3(512), dim3(256), 0, stream>>>(v, W1, b1, W2, b2, W3, b3, out);
    row_softmax<<<dim3(4 * NN), dim3(256), 0, stream>>>(out);
}